// Round 1
// 383.236 us; speedup vs baseline: 1.0358x; 1.0358x over previous
//
#include <hip/hip_runtime.h>

#define RES 32
#define R3 (RES * RES * RES)
#define HALF (R3 / 2)

// Native no-return fp32 atomic add (ds_add_f32 / global_atomic_add_f32).
// Plain atomicAdd(float*) lowers to a CAS retry loop without
// -munsafe-fp-atomics; with hot voxels that cost ~234 cyc/wave-instr (R3 pm).
__device__ __forceinline__ void fadd_native(float* p, float v) {
    unsafeAtomicAdd(p, v);
}

// ---------------------------------------------------------------------------
// K1a: partial coordinate sums, float4 loads. grid (8, B), block 256.
// NUMERICALLY FROZEN: summation order determines mean -> rintf voxel
// boundaries. Do not restructure (absmax margin is thin).
// ---------------------------------------------------------------------------
__global__ void sums_kernel(const float* __restrict__ coords,
                            float* __restrict__ accum, int N) {
    const int b = blockIdx.y;
    const int stride = gridDim.x * blockDim.x;
    const float* cb = coords + (size_t)b * 3 * N;
    const int nvec = N >> 2;
    const float4* c0 = (const float4*)cb;
    const float4* c1 = (const float4*)(cb + N);
    const float4* c2 = (const float4*)(cb + 2 * N);

    float s0 = 0.f, s1 = 0.f, s2 = 0.f;
    for (int n = blockIdx.x * blockDim.x + threadIdx.x; n < nvec; n += stride) {
        float4 a = c0[n]; s0 += (a.x + a.y) + (a.z + a.w);
        float4 c = c1[n]; s1 += (c.x + c.y) + (c.z + c.w);
        float4 d = c2[n]; s2 += (d.x + d.y) + (d.z + d.w);
    }
    if (blockIdx.x == 0 && threadIdx.x == 0) {
        for (int n = nvec << 2; n < N; ++n) {
            s0 += cb[n]; s1 += cb[N + n]; s2 += cb[2 * N + n];
        }
    }
    for (int off = 32; off; off >>= 1) {
        s0 += __shfl_down(s0, off);
        s1 += __shfl_down(s1, off);
        s2 += __shfl_down(s2, off);
    }
    __shared__ float r0[4], r1[4], r2[4];
    const int lane = threadIdx.x & 63, wv = threadIdx.x >> 6;
    if (lane == 0) { r0[wv] = s0; r1[wv] = s1; r2[wv] = s2; }
    __syncthreads();
    if (threadIdx.x == 0) {
        float t0 = 0.f, t1 = 0.f, t2 = 0.f;
        const int nw = blockDim.x >> 6;
        for (int w = 0; w < nw; ++w) { t0 += r0[w]; t1 += r1[w]; t2 += r2[w]; }
        fadd_native(&accum[b * 4 + 0], t0);
        fadd_native(&accum[b * 4 + 1], t1);
        fadd_native(&accum[b * 4 + 2], t2);
    }
}

// ---------------------------------------------------------------------------
// K1b: partial max squared centered norm, float4 loads. grid (8, B).
// NUMERICALLY FROZEN (same reason as K1a).
// ---------------------------------------------------------------------------
__global__ void maxn_kernel(const float* __restrict__ coords,
                            const float* __restrict__ accum,
                            unsigned* __restrict__ maxsq, int N) {
    const int b = blockIdx.y;
    const int stride = gridDim.x * blockDim.x;
    const float* cb = coords + (size_t)b * 3 * N;
    const float m0 = accum[b * 4 + 0] / (float)N;
    const float m1 = accum[b * 4 + 1] / (float)N;
    const float m2 = accum[b * 4 + 2] / (float)N;
    const int nvec = N >> 2;
    const float4* c0 = (const float4*)cb;
    const float4* c1 = (const float4*)(cb + N);
    const float4* c2 = (const float4*)(cb + 2 * N);

    float mx = 0.f;
    for (int n = blockIdx.x * blockDim.x + threadIdx.x; n < nvec; n += stride) {
        float4 a = c0[n], c = c1[n], d = c2[n];
        a.x -= m0; a.y -= m0; a.z -= m0; a.w -= m0;
        c.x -= m1; c.y -= m1; c.z -= m1; c.w -= m1;
        d.x -= m2; d.y -= m2; d.z -= m2; d.w -= m2;
        mx = fmaxf(mx, a.x * a.x + c.x * c.x + d.x * d.x);
        mx = fmaxf(mx, a.y * a.y + c.y * c.y + d.y * d.y);
        mx = fmaxf(mx, a.z * a.z + c.z * c.z + d.z * d.z);
        mx = fmaxf(mx, a.w * a.w + c.w * c.w + d.w * d.w);
    }
    if (blockIdx.x == 0 && threadIdx.x == 0) {
        for (int n = nvec << 2; n < N; ++n) {
            float a = cb[n] - m0, c = cb[N + n] - m1, d = cb[2 * N + n] - m2;
            mx = fmaxf(mx, a * a + c * c + d * d);
        }
    }
    for (int off = 32; off; off >>= 1) mx = fmaxf(mx, __shfl_down(mx, off));
    __shared__ float r0[4];
    const int lane = threadIdx.x & 63, wv = threadIdx.x >> 6;
    if (lane == 0) r0[wv] = mx;
    __syncthreads();
    if (threadIdx.x == 0) {
        const int nw = blockDim.x >> 6;
        for (int w = 0; w < nw; ++w) mx = fmaxf(mx, r0[w]);
        atomicMax(&maxsq[b], __float_as_uint(mx));  // int atomic: native
    }
}

// ---------------------------------------------------------------------------
// K2: per-point normalize + voxel index + counts, 4 points/thread.
// True division (not rcp-mul) to keep voxel indices bit-identical to ref.
// NUMERICALLY FROZEN.
// ---------------------------------------------------------------------------
__global__ void point_kernel(const float* __restrict__ coords,
                             const float* __restrict__ accum,
                             const unsigned* __restrict__ maxsq,
                             float* __restrict__ nc_out,
                             int* __restrict__ idx_out,
                             int* __restrict__ counts, int N) {
    const int n4 = blockIdx.x * blockDim.x + threadIdx.x;
    const int b = blockIdx.y;
    const int nvec = (N + 3) >> 2;
    if (n4 >= nvec) return;

    const float* cb = coords + (size_t)b * 3 * N;
    const float m0 = accum[b * 4 + 0] / (float)N;
    const float m1 = accum[b * 4 + 1] / (float)N;
    const float m2 = accum[b * 4 + 2] / (float)N;
    const float denom = 2.0f * sqrtf(__uint_as_float(maxsq[b]));
    float* ncb = nc_out + (size_t)b * 3 * N;
    int* irow = idx_out + (size_t)b * N;
    int* crow = counts + (size_t)b * R3;

    const int n0 = n4 << 2;
    if (n0 + 3 < N) {
        float4 a = *(const float4*)(cb + n0);
        float4 c = *(const float4*)(cb + N + n0);
        float4 d = *(const float4*)(cb + 2 * N + n0);
        float4 v0, v1, v2;
        int4 id;
        #define PROC(comp)                                                        \
        {                                                                         \
            float x = (a.comp - m0) / denom + 0.5f;                               \
            float y = (c.comp - m1) / denom + 0.5f;                               \
            float z = (d.comp - m2) / denom + 0.5f;                               \
            v0.comp = fminf(fmaxf(x * (float)RES, 0.f), (float)(RES - 1));        \
            v1.comp = fminf(fmaxf(y * (float)RES, 0.f), (float)(RES - 1));        \
            v2.comp = fminf(fmaxf(z * (float)RES, 0.f), (float)(RES - 1));        \
            id.comp = (int)rintf(v0.comp) * RES * RES                             \
                    + (int)rintf(v1.comp) * RES + (int)rintf(v2.comp);            \
        }
        PROC(x) PROC(y) PROC(z) PROC(w)
        #undef PROC
        *(float4*)(ncb + n0) = v0;
        *(float4*)(ncb + N + n0) = v1;
        *(float4*)(ncb + 2 * N + n0) = v2;
        *(int4*)(irow + n0) = id;
        atomicAdd(&crow[id.x], 1);
        atomicAdd(&crow[id.y], 1);
        atomicAdd(&crow[id.z], 1);
        atomicAdd(&crow[id.w], 1);
    } else {
        for (int n = n0; n < N; ++n) {
            float x = (cb[n] - m0) / denom + 0.5f;
            float y = (cb[N + n] - m1) / denom + 0.5f;
            float z = (cb[2 * N + n] - m2) / denom + 0.5f;
            float v0 = fminf(fmaxf(x * (float)RES, 0.f), (float)(RES - 1));
            float v1 = fminf(fmaxf(y * (float)RES, 0.f), (float)(RES - 1));
            float v2 = fminf(fmaxf(z * (float)RES, 0.f), (float)(RES - 1));
            ncb[n] = v0; ncb[N + n] = v1; ncb[2 * N + n] = v2;
            int id = (int)rintf(v0) * RES * RES + (int)rintf(v1) * RES + (int)rintf(v2);
            irow[n] = id;
            atomicAdd(&crow[id], 1);
        }
    }
}

// ---------------------------------------------------------------------------
// K3 v2: per-(b,d,half) LDS-privatized scatter-mean over HALF the voxel
// space. 64 KB LDS -> 2 blocks/CU = 32 waves/CU (was 1 block / 16 waves /
// 45% occupancy, latency-bound: VALUBusy 7.9%, HBM 13%). Each block scans
// all N points and predicates the ds_add on its half; the doubled feature
// read is an L3 hit (128 MB tensor, 256 MB Infinity Cache).
// __launch_bounds__(1024,8) pins VGPR<=64 so 2 blocks actually co-reside.
// Register double-buffer: next iteration's loads issue before this
// iteration's LDS atomics (atomics otherwise fence the scheduler).
// ---------------------------------------------------------------------------
__global__ __launch_bounds__(1024, 8) void reduce_kernel(
        const float* __restrict__ feats,
        const int* __restrict__ idx,
        const int* __restrict__ counts,
        float* __restrict__ vox, int D, int N) {
    const int d = blockIdx.x;
    const int b = blockIdx.y;
    const int lo = (int)blockIdx.z * HALF;   // voxel-range owned: [lo, lo+HALF)
    const int tid = threadIdx.x;

    __shared__ float acc[HALF];   // 65536 bytes
    {
        float4* a4 = (float4*)acc;
        const float4 z = make_float4(0.f, 0.f, 0.f, 0.f);
        for (int v = tid; v < (HALF >> 2); v += 1024) a4[v] = z;
    }
    __syncthreads();

    const float* frow = feats + ((size_t)b * D + d) * N;
    const int* irow = idx + (size_t)b * N;
    const int nvec = N >> 2;
    const float4* f4p = (const float4*)frow;
    const int4* i4p = (const int4*)irow;

    #define SCATTER4(f, i)                                                       \
    {                                                                            \
        unsigned a0 = (unsigned)((i).x - lo);                                    \
        if (a0 < (unsigned)HALF) fadd_native(&acc[a0], (f).x);                   \
        unsigned a1 = (unsigned)((i).y - lo);                                    \
        if (a1 < (unsigned)HALF) fadd_native(&acc[a1], (f).y);                   \
        unsigned a2 = (unsigned)((i).z - lo);                                    \
        if (a2 < (unsigned)HALF) fadd_native(&acc[a2], (f).z);                   \
        unsigned a3 = (unsigned)((i).w - lo);                                    \
        if (a3 < (unsigned)HALF) fadd_native(&acc[a3], (f).w);                   \
    }

    if (tid < nvec) {
        float4 f = f4p[tid];
        int4   i = i4p[tid];
        for (int n = tid + 1024; n < nvec; n += 1024) {
            float4 fn = f4p[n];          // prefetch next iteration before
            int4   in_ = i4p[n];         // issuing this iteration's atomics
            SCATTER4(f, i)
            f = fn; i = in_;
        }
        SCATTER4(f, i)
    }
    #undef SCATTER4

    if (tid == 0) {
        for (int n = nvec << 2; n < N; ++n) {
            unsigned a = (unsigned)(irow[n] - lo);
            if (a < (unsigned)HALF) fadd_native(&acc[a], frow[n]);
        }
    }
    __syncthreads();

    // Epilogue: divide by counts, write this block's half of the voxel grid.
    // __fdividef (2.5 ulp) is safe here: only output VALUES (tol ~2e-3),
    // voxel-index math in K2 is untouched.
    const int* crow = counts + (size_t)b * R3 + lo;
    float* vrow = vox + ((size_t)b * D + d) * R3 + lo;
    const int4* c4 = (const int4*)crow;
    float4* v4 = (float4*)vrow;
    for (int v = tid; v < (HALF >> 2); v += 1024) {
        int4 c = c4[v];
        float4 a = ((const float4*)acc)[v];
        a.x = __fdividef(a.x, (float)(c.x > 1 ? c.x : 1));
        a.y = __fdividef(a.y, (float)(c.y > 1 ? c.y : 1));
        a.z = __fdividef(a.z, (float)(c.z > 1 ? c.z : 1));
        a.w = __fdividef(a.w, (float)(c.w > 1 ? c.w : 1));
        v4[v] = a;
    }
}

extern "C" void kernel_launch(void* const* d_in, const int* in_sizes, int n_in,
                              void* d_out, int out_size, void* d_ws, size_t ws_size,
                              hipStream_t stream) {
    const float* feats  = (const float*)d_in[0];   // (B, D, N)
    const float* coords = (const float*)d_in[1];   // (B, 3, N)
    float* out = (float*)d_out;

    const int D = (int)(3LL * in_sizes[0] / in_sizes[1]);
    const int B = (int)((long long)(out_size - in_sizes[1]) / ((long long)D * R3));
    const int N = in_sizes[1] / (3 * B);

    float* vox_out = out;                          // (B, D, R3)
    float* nc_out  = out + (size_t)B * D * R3;     // (B, 3, N)

    // ws layout: [accum B*4 f @0][maxsq B u32 @1024][counts B*R3 i32 @4096][idx B*N i32]
    float*    accum  = (float*)d_ws;
    unsigned* maxsq  = (unsigned*)((char*)d_ws + 1024);
    int*      counts = (int*)((char*)d_ws + 4096);
    int*      idx    = (int*)((char*)d_ws + 4096 + (size_t)B * R3 * sizeof(int));

    hipMemsetAsync(d_ws, 0, 4096 + (size_t)B * R3 * sizeof(int), stream);

    sums_kernel <<<dim3(8, B), dim3(256), 0, stream>>>(coords, accum, N);
    maxn_kernel <<<dim3(8, B), dim3(256), 0, stream>>>(coords, accum, maxsq, N);

    const int nvec = (N + 3) >> 2;
    point_kernel<<<dim3((nvec + 255) / 256, B), dim3(256), 0, stream>>>(
        coords, accum, maxsq, nc_out, idx, counts, N);

    reduce_kernel<<<dim3(D, B, 2), dim3(1024), 0, stream>>>(
        feats, idx, counts, vox_out, D, N);
}